// Round 11
// baseline (380.519 us; speedup 1.0000x reference)
//
#include <hip/hip_runtime.h>
#include <hip/hip_bf16.h>

#define GN 50000
#define GE 800000
#define GD 96
#define GC 40
#define L2EPS 1e-12f
#define NBUCKET 6
#define BDIV 8334   // col/8334 -> 0..5 for col in [0,50000)

typedef __attribute__((ext_vector_type(8))) short short8v;   // 8 bf16 = 4 VGPR
typedef __attribute__((ext_vector_type(4))) float f32x4;

__device__ __forceinline__ unsigned f2bf(float x) {           // RNE float->bf16 bits
    union { float f; unsigned u; } v; v.f = x;
    return (v.u + 0x7fffu + ((v.u >> 16) & 1u)) >> 16;
}
__device__ __forceinline__ float bflo(unsigned u) { return __uint_as_float(u << 16); }
__device__ __forceinline__ float bfhi(unsigned u) { return __uint_as_float(u & 0xffff0000u); }

__device__ __forceinline__ int lbound(const int* __restrict__ row, int key) {
    int lo = 0, hi = GE;
    while (lo < hi) {
        int mid = (lo + hi) >> 1;
        if (row[mid] < key) lo = mid + 1; else hi = mid;
    }
    return lo;
}

// prep: rp[i]=lower_bound(row,i) ; degree histogram ; Wb1/Wb2 MFMA B-frag packs.
__global__ void prep_k(const int* __restrict__ row, const float* __restrict__ w1,
                       const float* __restrict__ w2, int* __restrict__ rp,
                       int* __restrict__ hist, unsigned* __restrict__ Wb1,
                       unsigned* __restrict__ Wb2) {
    int i = blockIdx.x * blockDim.x + threadIdx.x;
    if (i <= GN) {
        int lo = lbound(row, i);
        rp[i] = lo;
        if (i < GN) {
            int d = lbound(row, i + 1) - lo;
            if (d > 127) d = 127;
            atomicAdd(&hist[d], 1);
        }
    }
    if (i < 2 * 4608) {
        const float* W = (i < 4608) ? w1 : w2;
        unsigned* Wb   = (i < 4608) ? Wb1 : Wb2;
        int j = (i < 4608) ? i : i - 4608;
        int r = j & 3;
        int lane = (j >> 2) & 63;
        int frag = j >> 8;                 // 0..17
        int nt = frag / 3, kt = frag - nt * 3;
        int c = nt * 16 + (lane & 15);
        int k = kt * 32 + (lane >> 4) * 8 + r * 2;
        Wb[j] = f2bf(W[k * GD + c]) | (f2bf(W[(k + 1) * GD + c]) << 16);
    }
}

// counting-sort placement: perm = node ids ordered by degree (intra-class order
// atomic-nondeterministic -> affects schedule only, output values invariant).
__global__ void place_k(const int* __restrict__ rp, const int* __restrict__ hist,
                        int* __restrict__ cnt, int* __restrict__ perm) {
    int n = blockIdx.x * blockDim.x + threadIdx.x;
    if (n >= GN) return;
    int d = rp[n + 1] - rp[n];
    if (d > 127) d = 127;
    int base = 0;
    for (int k = 0; k < d; ++k) base += hist[k];
    perm[base + atomicAdd(&cnt[d], 1)] = n;
}

// wave-cooperative stable bucket sort of each node's edges by col/BDIV.
__global__ void bucket_k(const int* __restrict__ rp, const int* __restrict__ col,
                         const float* __restrict__ vals, int2* __restrict__ ep) {
    int idx = blockIdx.x * blockDim.x + threadIdx.x;
    int n = idx >> 4;
    if (n >= GN) return;
    int l = idx & 15;
    int shift = (threadIdx.x & 63) & 48;
    unsigned lt_mask = (1u << l) - 1u;
    int e0 = rp[n], e1 = rp[n + 1];

    int cnt[NBUCKET] = {0, 0, 0, 0, 0, 0};
    for (int be = e0; be < e1; be += 16) {
        int e = be + l;
        bool valid = e < e1;
        int key = valid ? (col[e] / BDIV) : -1;
#pragma unroll
        for (int q = 0; q < NBUCKET; ++q) {
            unsigned m = (unsigned)(__ballot(key == q) >> shift) & 0xffffu;
            cnt[q] += __popc(m);
        }
    }
    int off[NBUCKET];
    off[0] = e0;
#pragma unroll
    for (int q = 1; q < NBUCKET; ++q) off[q] = off[q - 1] + cnt[q - 1];

    for (int be = e0; be < e1; be += 16) {
        int e = be + l;
        bool valid = e < e1;
        int c = valid ? col[e] : 0;
        float v = valid ? vals[e] : 0.f;
        int key = valid ? (c / BDIV) : -1;
#pragma unroll
        for (int q = 0; q < NBUCKET; ++q) {
            unsigned m = (unsigned)(__ballot(key == q) >> shift) & 0xffffu;
            if (key == q)
                ep[off[q] + __popc(m & lt_mask)] = make_int2(c, __float_as_int(v));
            off[q] += __popc(m);
        }
    }
}

// O_bf16[N,96] = A_f32[N,96] @ W ; MFMA 16x16x32 bf16 with split-A (hi+lo -> A exact).
__global__ __launch_bounds__(64) void gemm_mfma_k(const float* __restrict__ A,
                                                  const uint4* __restrict__ Wb,
                                                  unsigned short* __restrict__ O) {
    const int tile = blockIdx.x;            // 0..3124
    const int l  = threadIdx.x;             // 0..63
    const int m  = l & 15;
    const int kg = l >> 4;

    const float* arow = A + (size_t)(tile * 16 + m) * GD + kg * 8;
    short8v ah[3], al[3];
#pragma unroll
    for (int kt = 0; kt < 3; ++kt) {
        const float4* ap = reinterpret_cast<const float4*>(arow + kt * 32);
        float4 x0 = ap[0], x1 = ap[1];
        uint4 H, L;
        H.x = f2bf(x0.x) | (f2bf(x0.y) << 16);
        H.y = f2bf(x0.z) | (f2bf(x0.w) << 16);
        H.z = f2bf(x1.x) | (f2bf(x1.y) << 16);
        H.w = f2bf(x1.z) | (f2bf(x1.w) << 16);
        L.x = f2bf(x0.x - bflo(H.x)) | (f2bf(x0.y - bfhi(H.x)) << 16);
        L.y = f2bf(x0.z - bflo(H.y)) | (f2bf(x0.w - bfhi(H.y)) << 16);
        L.z = f2bf(x1.x - bflo(H.z)) | (f2bf(x1.y - bfhi(H.z)) << 16);
        L.w = f2bf(x1.z - bflo(H.w)) | (f2bf(x1.w - bfhi(H.w)) << 16);
        union { uint4 u; short8v s; } ch, cl;
        ch.u = H; cl.u = L;
        ah[kt] = ch.s; al[kt] = cl.s;
    }

#pragma unroll
    for (int nt = 0; nt < 6; ++nt) {
        f32x4 acc = {0.f, 0.f, 0.f, 0.f};
#pragma unroll
        for (int kt = 0; kt < 3; ++kt) {
            union { uint4 u; short8v s; } b;
            b.u = Wb[(nt * 3 + kt) * 64 + l];
            acc = __builtin_amdgcn_mfma_f32_16x16x32_bf16(ah[kt], b.s, acc, 0, 0, 0);
            acc = __builtin_amdgcn_mfma_f32_16x16x32_bf16(al[kt], b.s, acc, 0, 0, 0);
        }
        int ccol = nt * 16 + m;
#pragma unroll
        for (int reg = 0; reg < 4; ++reg) {
            int rrow = tile * 16 + kg * 4 + reg;
            O[(size_t)rrow * GD + ccol] = (unsigned short)f2bf(acc[reg]);
        }
    }
}

#define FMA8(U, V)                                                    \
    a0 += (V) * bflo((U).x); a1 += (V) * bfhi((U).x);                 \
    a2 += (V) * bflo((U).y); a3 += (V) * bfhi((U).y);                 \
    a4 += (V) * bflo((U).z); a5 += (V) * bfhi((U).z);                 \
    a6 += (V) * bflo((U).w); a7 += (V) * bfhi((U).w);

// 12 threads/node, nodes in degree-sorted order via perm (wave load balance).
__global__ void spmm_relu_k(const int* __restrict__ rp, const int* __restrict__ perm,
                            const int2* __restrict__ ep,
                            const unsigned* __restrict__ Tb, float* __restrict__ H) {
    int idx = blockIdx.x * blockDim.x + threadIdx.x;
    int gid = idx / 12;
    if (gid >= GN) return;
    int n = perm[gid];
    int t = idx - gid * 12;
    int e0 = rp[n], e1 = rp[n + 1];
    float a0=0,a1=0,a2=0,a3=0,a4=0,a5=0,a6=0,a7=0;
    int e = e0;
    for (; e + 4 <= e1; e += 4) {
        int2 p0 = ep[e], p1 = ep[e+1], p2 = ep[e+2], p3 = ep[e+3];
        uint4 u0 = *reinterpret_cast<const uint4*>(Tb + (size_t)p0.x * 48 + t * 4);
        uint4 u1 = *reinterpret_cast<const uint4*>(Tb + (size_t)p1.x * 48 + t * 4);
        uint4 u2 = *reinterpret_cast<const uint4*>(Tb + (size_t)p2.x * 48 + t * 4);
        uint4 u3 = *reinterpret_cast<const uint4*>(Tb + (size_t)p3.x * 48 + t * 4);
        FMA8(u0, __int_as_float(p0.y)) FMA8(u1, __int_as_float(p1.y))
        FMA8(u2, __int_as_float(p2.y)) FMA8(u3, __int_as_float(p3.y))
    }
    for (; e < e1; ++e) {
        int2 p = ep[e];
        uint4 u = *reinterpret_cast<const uint4*>(Tb + (size_t)p.x * 48 + t * 4);
        FMA8(u, __int_as_float(p.y))
    }
    float4* hr = reinterpret_cast<float4*>(H + (size_t)n * GD + t * 8);
    hr[0] = make_float4(fmaxf(a0,0.f), fmaxf(a1,0.f), fmaxf(a2,0.f), fmaxf(a3,0.f));
    hr[1] = make_float4(fmaxf(a4,0.f), fmaxf(a5,0.f), fmaxf(a6,0.f), fmaxf(a7,0.f));
}

#define FMA12(U, W_, V)                                               \
    a0 += (V) * bflo((U).x); a1 += (V) * bfhi((U).x);                 \
    a2 += (V) * bflo((U).y); a3 += (V) * bfhi((U).y);                 \
    a4 += (V) * bflo((U).z); a5 += (V) * bfhi((U).z);                 \
    a6 += (V) * bflo((U).w); a7 += (V) * bfhi((U).w);                 \
    a8 += (V) * bflo((W_).x); a9 += (V) * bfhi((W_).x);               \
    a10 += (V) * bflo((W_).y); a11 += (V) * bfhi((W_).y);

// 8 threads/node (degree-sorted); shuffle l2-norm across the 8-lane group.
__global__ void spmm_relu_norm_k(const int* __restrict__ rp, const int* __restrict__ perm,
                                 const int2* __restrict__ ep,
                                 const unsigned* __restrict__ Tb, float* __restrict__ H) {
    int idx = blockIdx.x * blockDim.x + threadIdx.x;
    int gid = idx >> 3;
    if (gid >= GN) return;
    int n = perm[gid];
    int t = idx & 7;
    int e0 = rp[n], e1 = rp[n + 1];
    float a0=0,a1=0,a2=0,a3=0,a4=0,a5=0,a6=0,a7=0,a8=0,a9=0,a10=0,a11=0;
    int e = e0;
    for (; e + 2 <= e1; e += 2) {
        int2 p0 = ep[e], p1 = ep[e+1];
        const unsigned* r0p = Tb + (size_t)p0.x * 48;
        const unsigned* r1p = Tb + (size_t)p1.x * 48;
        uint4 u0 = *reinterpret_cast<const uint4*>(r0p + t * 4);
        uint2 w0 = *reinterpret_cast<const uint2*>(r0p + 32 + t * 2);
        uint4 u1 = *reinterpret_cast<const uint4*>(r1p + t * 4);
        uint2 w1 = *reinterpret_cast<const uint2*>(r1p + 32 + t * 2);
        FMA12(u0, w0, __int_as_float(p0.y)) FMA12(u1, w1, __int_as_float(p1.y))
    }
    for (; e < e1; ++e) {
        int2 p = ep[e];
        const unsigned* r = Tb + (size_t)p.x * 48;
        uint4 u = *reinterpret_cast<const uint4*>(r + t * 4);
        uint2 w = *reinterpret_cast<const uint2*>(r + 32 + t * 2);
        FMA12(u, w, __int_as_float(p.y))
    }
    a0=fmaxf(a0,0.f); a1=fmaxf(a1,0.f); a2=fmaxf(a2,0.f); a3=fmaxf(a3,0.f);
    a4=fmaxf(a4,0.f); a5=fmaxf(a5,0.f); a6=fmaxf(a6,0.f); a7=fmaxf(a7,0.f);
    a8=fmaxf(a8,0.f); a9=fmaxf(a9,0.f); a10=fmaxf(a10,0.f); a11=fmaxf(a11,0.f);
    float ss = a0*a0+a1*a1+a2*a2+a3*a3+a4*a4+a5*a5+a6*a6+a7*a7+a8*a8+a9*a9+a10*a10+a11*a11;
    ss += __shfl_xor(ss, 1);
    ss += __shfl_xor(ss, 2);
    ss += __shfl_xor(ss, 4);
    float s = rsqrtf(fmaxf(ss, L2EPS));
    a0*=s; a1*=s; a2*=s; a3*=s; a4*=s; a5*=s;
    a6*=s; a7*=s; a8*=s; a9*=s; a10*=s; a11*=s;
    float4* hr = reinterpret_cast<float4*>(H + (size_t)n * GD + t * 8);
    hr[0] = make_float4(a0, a1, a2, a3);
    hr[1] = make_float4(a4, a5, a6, a7);
    *reinterpret_cast<float4*>(H + (size_t)n * GD + 64 + t * 4) =
        make_float4(a8, a9, a10, a11);
}

// logits[N,40] = A[N,96] @ WC[96,40] + bc; 4 rows x 4 cols per thread, WC in LDS
__global__ void cls_gemm_k(const float* __restrict__ A, const float* __restrict__ WC,
                           const float* __restrict__ BC, float* __restrict__ L) {
    __shared__ float4 w4[GD * 10];
    const float4* W4 = reinterpret_cast<const float4*>(WC);
    for (int i = threadIdx.x; i < GD * 10; i += blockDim.x) w4[i] = W4[i];
    __syncthreads();
    int idx = blockIdx.x * blockDim.x + threadIdx.x;
    if (idx >= (GN / 4) * 10) return;
    int rq = idx / 10;
    int q  = idx - rq * 10;
    int r0 = rq * 4;
    const float* a = A + (size_t)r0 * GD;
    float4 acc0 = {0,0,0,0}, acc1 = {0,0,0,0}, acc2 = {0,0,0,0}, acc3 = {0,0,0,0};
    for (int k0 = 0; k0 < GD; k0 += 4) {
        float4 a0 = *reinterpret_cast<const float4*>(a + k0);
        float4 a1 = *reinterpret_cast<const float4*>(a + GD + k0);
        float4 a2 = *reinterpret_cast<const float4*>(a + 2 * GD + k0);
        float4 a3 = *reinterpret_cast<const float4*>(a + 3 * GD + k0);
#pragma unroll
        for (int kk = 0; kk < 4; ++kk) {
            float4 w = w4[(k0 + kk) * 10 + q];
            float s0 = ((const float*)&a0)[kk];
            float s1 = ((const float*)&a1)[kk];
            float s2 = ((const float*)&a2)[kk];
            float s3 = ((const float*)&a3)[kk];
            acc0.x += s0 * w.x; acc0.y += s0 * w.y; acc0.z += s0 * w.z; acc0.w += s0 * w.w;
            acc1.x += s1 * w.x; acc1.y += s1 * w.y; acc1.z += s1 * w.z; acc1.w += s1 * w.w;
            acc2.x += s2 * w.x; acc2.y += s2 * w.y; acc2.z += s2 * w.z; acc2.w += s2 * w.w;
            acc3.x += s3 * w.x; acc3.y += s3 * w.y; acc3.z += s3 * w.z; acc3.w += s3 * w.w;
        }
    }
    float4 b = *reinterpret_cast<const float4*>(BC + q * 4);
    acc0.x += b.x; acc0.y += b.y; acc0.z += b.z; acc0.w += b.w;
    acc1.x += b.x; acc1.y += b.y; acc1.z += b.z; acc1.w += b.w;
    acc2.x += b.x; acc2.y += b.y; acc2.z += b.z; acc2.w += b.w;
    acc3.x += b.x; acc3.y += b.y; acc3.z += b.z; acc3.w += b.w;
    float4* L4 = reinterpret_cast<float4*>(L);
    L4[(size_t)(r0 + 0) * 10 + q] = acc0;
    L4[(size_t)(r0 + 1) * 10 + q] = acc1;
    L4[(size_t)(r0 + 2) * 10 + q] = acc2;
    L4[(size_t)(r0 + 3) * 10 + q] = acc3;
}

// thread per node: softmax over 40 logits
__global__ void softmax_k(const float* __restrict__ L, float* __restrict__ PROBS) {
    int n = blockIdx.x * blockDim.x + threadIdx.x;
    if (n >= GN) return;
    const float4* lr = reinterpret_cast<const float4*>(L + (size_t)n * GC);
    float4 v[10];
#pragma unroll
    for (int i = 0; i < 10; ++i) v[i] = lr[i];
    float m = -1e30f;
#pragma unroll
    for (int i = 0; i < 10; ++i)
        m = fmaxf(m, fmaxf(fmaxf(v[i].x, v[i].y), fmaxf(v[i].z, v[i].w)));
    float sum = 0.f;
#pragma unroll
    for (int i = 0; i < 10; ++i) {
        v[i].x = __expf(v[i].x - m); v[i].y = __expf(v[i].y - m);
        v[i].z = __expf(v[i].z - m); v[i].w = __expf(v[i].w - m);
        sum += v[i].x + v[i].y + v[i].z + v[i].w;
    }
    float inv = 1.f / sum;
    float4* pr = reinterpret_cast<float4*>(PROBS + (size_t)n * GC);
#pragma unroll
    for (int i = 0; i < 10; ++i) {
        v[i].x *= inv; v[i].y *= inv; v[i].z *= inv; v[i].w *= inv;
        pr[i] = v[i];
    }
}

extern "C" void kernel_launch(void* const* d_in, const int* in_sizes, int n_in,
                              void* d_out, int out_size, void* d_ws, size_t ws_size,
                              hipStream_t stream) {
    const int*   row  = (const int*)d_in[0];
    const int*   col  = (const int*)d_in[1];
    const float* vals = (const float*)d_in[2];
    const float* x    = (const float*)d_in[3];
    const float* w1   = (const float*)d_in[4];
    const float* w2   = (const float*)d_in[5];
    const float* wc   = (const float*)d_in[6];
    const float* bc   = (const float*)d_in[7];

    float* out   = (float*)d_out;                 // [N, D]
    float* probs = out + (size_t)GN * GD;         // [N, C]

    char*  ws  = (char*)d_ws;
    int*   rp  = (int*)ws;                                        // (N+1) ints
    size_t off = (((size_t)(GN + 1) * 4) + 511) & ~(size_t)511;
    unsigned* buf = (unsigned*)(ws + off);        // bf16 [N,96] (48 uints/row); reused as f32 logits
    off += (size_t)GN * GD * 4;
    off = (off + 511) & ~(size_t)511;
    int2* ep   = (int2*)(ws + off);               // [E] bucketed packed edges
    off += (size_t)GE * 8;
    off = (off + 511) & ~(size_t)511;
    unsigned* Wb1 = (unsigned*)(ws + off);        // 4608 uints MFMA B-frags of w1
    unsigned* Wb2 = Wb1 + 4608;
    off += 2 * 4608 * 4;
    off = (off + 511) & ~(size_t)511;
    int* hist = (int*)(ws + off);                 // 128 ints
    int* cnt  = hist + 128;                       // 128 ints
    off += 256 * 4;
    off = (off + 511) & ~(size_t)511;
    int* perm = (int*)(ws + off);                 // GN ints, degree-sorted node order

    hipMemsetAsync(hist, 0, 256 * 4, stream);     // hist + cnt
    // rp + degree hist + W packs
    prep_k<<<(GN + 1 + 255) / 256, 256, 0, stream>>>(row, w1, w2, rp, hist, Wb1, Wb2);
    // degree-sorted permutation (counting sort)
    place_k<<<(GN + 255) / 256, 256, 0, stream>>>(rp, hist, cnt, perm);
    // wave-cooperative bucket sort of edges (col-range phases for L2 locality)
    bucket_k<<<(GN * 16) / 256, 256, 0, stream>>>(rp, col, vals, ep);
    // t1 = bf16(x @ w1)
    gemm_mfma_k<<<GN / 16, 64, 0, stream>>>(x, (const uint4*)Wb1, (unsigned short*)buf);
    // h1 = relu(A @ t1) -> d_out (f32)
    spmm_relu_k<<<(GN * 12 + 255) / 256, 256, 0, stream>>>(rp, perm, ep, buf, out);
    // t2 = bf16(h1 @ w2)
    gemm_mfma_k<<<GN / 16, 64, 0, stream>>>(out, (const uint4*)Wb2, (unsigned short*)buf);
    // out = l2norm(relu(A @ t2))
    spmm_relu_norm_k<<<(GN * 8 + 255) / 256, 256, 0, stream>>>(rp, perm, ep, buf, out);
    // logits = out @ wc + bc -> buf (f32) ; probs = softmax(logits)
    cls_gemm_k<<<((GN / 4) * 10 + 255) / 256, 256, 0, stream>>>(out, wc, bc, (float*)buf);
    softmax_k<<<(GN + 255) / 256, 256, 0, stream>>>((float*)buf, probs);
}

// Round 12
// 101.683 us; speedup vs baseline: 3.7422x; 3.7422x over previous
//
#include <hip/hip_runtime.h>
#include <hip/hip_bf16.h>

#define GN 50000
#define GE 800000
#define GD 96
#define GC 40
#define L2EPS 1e-12f

typedef __attribute__((ext_vector_type(8))) short short8v;   // 8 bf16 = 4 VGPR
typedef __attribute__((ext_vector_type(4))) float f32x4;

__device__ __forceinline__ unsigned f2bf(float x) {           // RNE float->bf16 bits
    union { float f; unsigned u; } v; v.f = x;
    return (v.u + 0x7fffu + ((v.u >> 16) & 1u)) >> 16;
}
__device__ __forceinline__ float bflo(unsigned u) { return __uint_as_float(u << 16); }
__device__ __forceinline__ float bfhi(unsigned u) { return __uint_as_float(u & 0xffff0000u); }

__device__ __forceinline__ int lbound(const int* __restrict__ row, int key) {
    int lo = 0, hi = GE;
    while (lo < hi) {
        int mid = (lo + hi) >> 1;
        if (row[mid] < key) lo = mid + 1; else hi = mid;
    }
    return lo;
}

// prep: rp[i]=lower_bound(row,i) ; Wb1/Wb2 = MFMA B-fragment packs of w1/w2.
// (NO atomics — R11 lesson: per-node atomics to a tiny table serialize ~100µs.)
__global__ void prep_k(const int* __restrict__ row, const float* __restrict__ w1,
                       const float* __restrict__ w2, int* __restrict__ rp,
                       unsigned* __restrict__ Wb1, unsigned* __restrict__ Wb2) {
    int i = blockIdx.x * blockDim.x + threadIdx.x;
    if (i <= GN) rp[i] = lbound(row, i);
    if (i < 2 * 4608) {
        const float* W = (i < 4608) ? w1 : w2;
        unsigned* Wb   = (i < 4608) ? Wb1 : Wb2;
        int j = (i < 4608) ? i : i - 4608;
        int r = j & 3;
        int lane = (j >> 2) & 63;
        int frag = j >> 8;                 // 0..17
        int nt = frag / 3, kt = frag - nt * 3;
        int c = nt * 16 + (lane & 15);
        int k = kt * 32 + (lane >> 4) * 8 + r * 2;
        Wb[j] = f2bf(W[k * GD + c]) | (f2bf(W[(k + 1) * GD + c]) << 16);
    }
}

// O_bf16[N,96] = A_f32[N,96] @ W ; MFMA 16x16x32 bf16 with split-A (hi+lo -> A exact).
__global__ __launch_bounds__(64) void gemm_mfma_k(const float* __restrict__ A,
                                                  const uint4* __restrict__ Wb,
                                                  unsigned short* __restrict__ O) {
    const int tile = blockIdx.x;            // 0..3124
    const int l  = threadIdx.x;             // 0..63
    const int m  = l & 15;
    const int kg = l >> 4;

    const float* arow = A + (size_t)(tile * 16 + m) * GD + kg * 8;
    short8v ah[3], al[3];
#pragma unroll
    for (int kt = 0; kt < 3; ++kt) {
        const float4* ap = reinterpret_cast<const float4*>(arow + kt * 32);
        float4 x0 = ap[0], x1 = ap[1];
        uint4 H, L;
        H.x = f2bf(x0.x) | (f2bf(x0.y) << 16);
        H.y = f2bf(x0.z) | (f2bf(x0.w) << 16);
        H.z = f2bf(x1.x) | (f2bf(x1.y) << 16);
        H.w = f2bf(x1.z) | (f2bf(x1.w) << 16);
        L.x = f2bf(x0.x - bflo(H.x)) | (f2bf(x0.y - bfhi(H.x)) << 16);
        L.y = f2bf(x0.z - bflo(H.y)) | (f2bf(x0.w - bfhi(H.y)) << 16);
        L.z = f2bf(x1.x - bflo(H.z)) | (f2bf(x1.y - bfhi(H.z)) << 16);
        L.w = f2bf(x1.z - bflo(H.w)) | (f2bf(x1.w - bfhi(H.w)) << 16);
        union { uint4 u; short8v s; } ch, cl;
        ch.u = H; cl.u = L;
        ah[kt] = ch.s; al[kt] = cl.s;
    }

#pragma unroll
    for (int nt = 0; nt < 6; ++nt) {
        f32x4 acc = {0.f, 0.f, 0.f, 0.f};
#pragma unroll
        for (int kt = 0; kt < 3; ++kt) {
            union { uint4 u; short8v s; } b;
            b.u = Wb[(nt * 3 + kt) * 64 + l];
            acc = __builtin_amdgcn_mfma_f32_16x16x32_bf16(ah[kt], b.s, acc, 0, 0, 0);
            acc = __builtin_amdgcn_mfma_f32_16x16x32_bf16(al[kt], b.s, acc, 0, 0, 0);
        }
        int ccol = nt * 16 + m;
#pragma unroll
        for (int reg = 0; reg < 4; ++reg) {
            int rrow = tile * 16 + kg * 4 + reg;
            O[(size_t)rrow * GD + ccol] = (unsigned short)f2bf(acc[reg]);
        }
    }
}

#define FMA8(U, V)                                                    \
    a0 += (V) * bflo((U).x); a1 += (V) * bfhi((U).x);                 \
    a2 += (V) * bflo((U).y); a3 += (V) * bfhi((U).y);                 \
    a4 += (V) * bflo((U).z); a5 += (V) * bfhi((U).z);                 \
    a6 += (V) * bflo((U).w); a7 += (V) * bfhi((U).w);

// 12 threads/node; lane t gathers one uint4 (cols t*8..t*8+7) per edge; unroll-4.
__global__ void spmm_relu_k(const int* __restrict__ rp, const int* __restrict__ col,
                            const float* __restrict__ vals,
                            const unsigned* __restrict__ Tb, float* __restrict__ H) {
    int idx = blockIdx.x * blockDim.x + threadIdx.x;
    int n = idx / 12;
    if (n >= GN) return;
    int t = idx - n * 12;
    int e0 = rp[n], e1 = rp[n + 1];
    float a0=0,a1=0,a2=0,a3=0,a4=0,a5=0,a6=0,a7=0;
    int e = e0;
    for (; e + 4 <= e1; e += 4) {
        int c0 = col[e], c1 = col[e+1], c2 = col[e+2], c3 = col[e+3];
        float v0 = vals[e], v1 = vals[e+1], v2 = vals[e+2], v3 = vals[e+3];
        uint4 u0 = *reinterpret_cast<const uint4*>(Tb + (size_t)c0 * 48 + t * 4);
        uint4 u1 = *reinterpret_cast<const uint4*>(Tb + (size_t)c1 * 48 + t * 4);
        uint4 u2 = *reinterpret_cast<const uint4*>(Tb + (size_t)c2 * 48 + t * 4);
        uint4 u3 = *reinterpret_cast<const uint4*>(Tb + (size_t)c3 * 48 + t * 4);
        FMA8(u0, v0) FMA8(u1, v1) FMA8(u2, v2) FMA8(u3, v3)
    }
    for (; e < e1; ++e) {
        float v = vals[e];
        uint4 u = *reinterpret_cast<const uint4*>(Tb + (size_t)col[e] * 48 + t * 4);
        FMA8(u, v)
    }
    float4* hr = reinterpret_cast<float4*>(H + (size_t)n * GD + t * 8);
    hr[0] = make_float4(fmaxf(a0,0.f), fmaxf(a1,0.f), fmaxf(a2,0.f), fmaxf(a3,0.f));
    hr[1] = make_float4(fmaxf(a4,0.f), fmaxf(a5,0.f), fmaxf(a6,0.f), fmaxf(a7,0.f));
}

#define FMA12(U, W_, V)                                               \
    a0 += (V) * bflo((U).x); a1 += (V) * bfhi((U).x);                 \
    a2 += (V) * bflo((U).y); a3 += (V) * bfhi((U).y);                 \
    a4 += (V) * bflo((U).z); a5 += (V) * bfhi((U).z);                 \
    a6 += (V) * bflo((U).w); a7 += (V) * bfhi((U).w);                 \
    a8 += (V) * bflo((W_).x); a9 += (V) * bfhi((W_).x);               \
    a10 += (V) * bflo((W_).y); a11 += (V) * bfhi((W_).y);

// 8 threads/node; lane t owns cols [8t..8t+7] + [64+4t..64+4t+3]; shuffle l2-norm.
__global__ void spmm_relu_norm_k(const int* __restrict__ rp, const int* __restrict__ col,
                                 const float* __restrict__ vals,
                                 const unsigned* __restrict__ Tb, float* __restrict__ H) {
    int idx = blockIdx.x * blockDim.x + threadIdx.x;
    int n = idx >> 3;
    if (n >= GN) return;
    int t = idx & 7;
    int e0 = rp[n], e1 = rp[n + 1];
    float a0=0,a1=0,a2=0,a3=0,a4=0,a5=0,a6=0,a7=0,a8=0,a9=0,a10=0,a11=0;
    int e = e0;
    for (; e + 4 <= e1; e += 4) {
        int c0 = col[e], c1 = col[e+1], c2 = col[e+2], c3 = col[e+3];
        float v0 = vals[e], v1 = vals[e+1], v2 = vals[e+2], v3 = vals[e+3];
        const unsigned* r0p = Tb + (size_t)c0 * 48;
        const unsigned* r1p = Tb + (size_t)c1 * 48;
        const unsigned* r2p = Tb + (size_t)c2 * 48;
        const unsigned* r3p = Tb + (size_t)c3 * 48;
        uint4 u0 = *reinterpret_cast<const uint4*>(r0p + t * 4);
        uint2 w0 = *reinterpret_cast<const uint2*>(r0p + 32 + t * 2);
        uint4 u1 = *reinterpret_cast<const uint4*>(r1p + t * 4);
        uint2 w1 = *reinterpret_cast<const uint2*>(r1p + 32 + t * 2);
        uint4 u2 = *reinterpret_cast<const uint4*>(r2p + t * 4);
        uint2 w2 = *reinterpret_cast<const uint2*>(r2p + 32 + t * 2);
        uint4 u3 = *reinterpret_cast<const uint4*>(r3p + t * 4);
        uint2 w3 = *reinterpret_cast<const uint2*>(r3p + 32 + t * 2);
        FMA12(u0, w0, v0) FMA12(u1, w1, v1) FMA12(u2, w2, v2) FMA12(u3, w3, v3)
    }
    for (; e < e1; ++e) {
        float v = vals[e];
        const unsigned* r = Tb + (size_t)col[e] * 48;
        uint4 u = *reinterpret_cast<const uint4*>(r + t * 4);
        uint2 w = *reinterpret_cast<const uint2*>(r + 32 + t * 2);
        FMA12(u, w, v)
    }
    a0=fmaxf(a0,0.f); a1=fmaxf(a1,0.f); a2=fmaxf(a2,0.f); a3=fmaxf(a3,0.f);
    a4=fmaxf(a4,0.f); a5=fmaxf(a5,0.f); a6=fmaxf(a6,0.f); a7=fmaxf(a7,0.f);
    a8=fmaxf(a8,0.f); a9=fmaxf(a9,0.f); a10=fmaxf(a10,0.f); a11=fmaxf(a11,0.f);
    float ss = a0*a0+a1*a1+a2*a2+a3*a3+a4*a4+a5*a5+a6*a6+a7*a7+a8*a8+a9*a9+a10*a10+a11*a11;
    ss += __shfl_xor(ss, 1);
    ss += __shfl_xor(ss, 2);
    ss += __shfl_xor(ss, 4);
    float s = rsqrtf(fmaxf(ss, L2EPS));
    a0*=s; a1*=s; a2*=s; a3*=s; a4*=s; a5*=s;
    a6*=s; a7*=s; a8*=s; a9*=s; a10*=s; a11*=s;
    float4* hr = reinterpret_cast<float4*>(H + (size_t)n * GD + t * 8);
    hr[0] = make_float4(a0, a1, a2, a3);
    hr[1] = make_float4(a4, a5, a6, a7);
    *reinterpret_cast<float4*>(H + (size_t)n * GD + 64 + t * 4) =
        make_float4(a8, a9, a10, a11);
}

// fused classifier + softmax: 320 threads = 32 row-quads (10 threads each, 4x4 tile),
// logits to LDS, then 1 thread per row does softmax and writes probs.
__global__ __launch_bounds__(320) void cls_sm_k(const float* __restrict__ A,
                                                const float* __restrict__ WC,
                                                const float* __restrict__ BC,
                                                float* __restrict__ PROBS) {
    __shared__ float4 w4[GD * 10];         // 15360 B
    __shared__ float lg[128][GC];          // 20480 B
    const float4* W4 = reinterpret_cast<const float4*>(WC);
    for (int i = threadIdx.x; i < GD * 10; i += 320) w4[i] = W4[i];
    __syncthreads();

    const int tid = threadIdx.x;
    const int lq = tid / 10;               // 0..31 local row-quad
    const int q  = tid - lq * 10;          // 0..9 col-quad
    const int r0 = (blockIdx.x * 32 + lq) * 4;
    if (r0 < GN) {
        const float* a = A + (size_t)r0 * GD;
        float4 acc0 = {0,0,0,0}, acc1 = {0,0,0,0}, acc2 = {0,0,0,0}, acc3 = {0,0,0,0};
        for (int k0 = 0; k0 < GD; k0 += 4) {
            float4 a0 = *reinterpret_cast<const float4*>(a + k0);
            float4 a1 = *reinterpret_cast<const float4*>(a + GD + k0);
            float4 a2 = *reinterpret_cast<const float4*>(a + 2 * GD + k0);
            float4 a3 = *reinterpret_cast<const float4*>(a + 3 * GD + k0);
#pragma unroll
            for (int kk = 0; kk < 4; ++kk) {
                float4 w = w4[(k0 + kk) * 10 + q];
                float s0 = ((const float*)&a0)[kk];
                float s1 = ((const float*)&a1)[kk];
                float s2 = ((const float*)&a2)[kk];
                float s3 = ((const float*)&a3)[kk];
                acc0.x += s0 * w.x; acc0.y += s0 * w.y; acc0.z += s0 * w.z; acc0.w += s0 * w.w;
                acc1.x += s1 * w.x; acc1.y += s1 * w.y; acc1.z += s1 * w.z; acc1.w += s1 * w.w;
                acc2.x += s2 * w.x; acc2.y += s2 * w.y; acc2.z += s2 * w.z; acc2.w += s2 * w.w;
                acc3.x += s3 * w.x; acc3.y += s3 * w.y; acc3.z += s3 * w.z; acc3.w += s3 * w.w;
            }
        }
        float4 b = *reinterpret_cast<const float4*>(BC + q * 4);
        acc0.x += b.x; acc0.y += b.y; acc0.z += b.z; acc0.w += b.w;
        acc1.x += b.x; acc1.y += b.y; acc1.z += b.z; acc1.w += b.w;
        acc2.x += b.x; acc2.y += b.y; acc2.z += b.z; acc2.w += b.w;
        acc3.x += b.x; acc3.y += b.y; acc3.z += b.z; acc3.w += b.w;
        *reinterpret_cast<float4*>(&lg[lq * 4 + 0][q * 4]) = acc0;
        *reinterpret_cast<float4*>(&lg[lq * 4 + 1][q * 4]) = acc1;
        *reinterpret_cast<float4*>(&lg[lq * 4 + 2][q * 4]) = acc2;
        *reinterpret_cast<float4*>(&lg[lq * 4 + 3][q * 4]) = acc3;
    }
    __syncthreads();

    if (tid < 128) {
        int r = blockIdx.x * 128 + tid;
        if (r < GN) {
            const float* row = lg[tid];
            float m = row[0];
#pragma unroll
            for (int c = 1; c < GC; ++c) m = fmaxf(m, row[c]);
            float ex[GC];
            float sum = 0.f;
#pragma unroll
            for (int c = 0; c < GC; ++c) { ex[c] = __expf(row[c] - m); sum += ex[c]; }
            float inv = 1.f / sum;
            float4* pr = reinterpret_cast<float4*>(PROBS + (size_t)r * GC);
#pragma unroll
            for (int i = 0; i < 10; ++i)
                pr[i] = make_float4(ex[i*4] * inv, ex[i*4+1] * inv,
                                    ex[i*4+2] * inv, ex[i*4+3] * inv);
        }
    }
}

extern "C" void kernel_launch(void* const* d_in, const int* in_sizes, int n_in,
                              void* d_out, int out_size, void* d_ws, size_t ws_size,
                              hipStream_t stream) {
    const int*   row  = (const int*)d_in[0];
    const int*   col  = (const int*)d_in[1];
    const float* vals = (const float*)d_in[2];
    const float* x    = (const float*)d_in[3];
    const float* w1   = (const float*)d_in[4];
    const float* w2   = (const float*)d_in[5];
    const float* wc   = (const float*)d_in[6];
    const float* bc   = (const float*)d_in[7];

    float* out   = (float*)d_out;                 // [N, D]
    float* probs = out + (size_t)GN * GD;         // [N, C]

    char*  ws  = (char*)d_ws;
    int*   rp  = (int*)ws;                                        // (N+1) ints
    size_t off = (((size_t)(GN + 1) * 4) + 511) & ~(size_t)511;
    unsigned* buf = (unsigned*)(ws + off);        // bf16 [N,96] (48 uints/row)
    off += (size_t)GN * GD * 4;
    off = (off + 511) & ~(size_t)511;
    unsigned* Wb1 = (unsigned*)(ws + off);        // 4608 uints MFMA B-frags of w1
    unsigned* Wb2 = Wb1 + 4608;

    // rp + W packs
    prep_k<<<(GN + 1 + 255) / 256, 256, 0, stream>>>(row, w1, w2, rp, Wb1, Wb2);
    // t1 = bf16(x @ w1)
    gemm_mfma_k<<<GN / 16, 64, 0, stream>>>(x, (const uint4*)Wb1, (unsigned short*)buf);
    // h1 = relu(A @ t1) -> d_out (f32)
    spmm_relu_k<<<(GN * 12 + 255) / 256, 256, 0, stream>>>(rp, col, vals, buf, out);
    // t2 = bf16(h1 @ w2)
    gemm_mfma_k<<<GN / 16, 64, 0, stream>>>(out, (const uint4*)Wb2, (unsigned short*)buf);
    // out = l2norm(relu(A @ t2))
    spmm_relu_norm_k<<<(GN * 8 + 255) / 256, 256, 0, stream>>>(rp, col, vals, buf, out);
    // probs = softmax(out @ wc + bc), fused
    cls_sm_k<<<(GN + 127) / 128, 320, 0, stream>>>(out, wc, bc, probs);
}